// Round 1
// baseline (70.208 us; speedup 1.0000x reference)
//
#include <hip/hip_runtime.h>

// UFLAttention collapses: softmax over the contracted axis sums to 1,
// so combined[b,i] = (x[b,i]*sum_h(Wv[i,h]) + sum_h(bv[i,h])) / sqrt(D).
// Then y = relu(x + combined), out = layernorm(y)*gamma + beta.
// Wq/bq/Wk/bk are never read.

constexpr int B_DIM = 512;
constexpr int D_DIM = 256;
constexpr int H_DIM = 8;

__global__ __launch_bounds__(256) void ufl_collapsed_kernel(
    const float* __restrict__ x,      // [B, D]
    const float* __restrict__ Wv,     // [D, H]
    const float* __restrict__ bv,     // [D, H]
    const float* __restrict__ gamma,  // [D]
    const float* __restrict__ beta,   // [D]
    float* __restrict__ out)          // [B, D]
{
    const int b = blockIdx.x;   // batch row
    const int i = threadIdx.x;  // feature index, 0..255

    const float xv = x[b * D_DIM + i];

    // sum Wv[i,:] and bv[i,:] over heads (8 contiguous floats; L1-cached)
    float svw = 0.0f, svb = 0.0f;
#pragma unroll
    for (int h = 0; h < H_DIM; ++h) {
        svw += Wv[i * H_DIM + h];
        svb += bv[i * H_DIM + h];
    }

    // combined = v_rowsum / sqrt(D); sqrt(256) = 16
    const float combined = (xv * svw + svb) * 0.0625f;
    const float y = fmaxf(xv + combined, 0.0f);

    // Block reduction over D=256 for mean and mean-of-squares.
    float s = y;
    float ss = y * y;
#pragma unroll
    for (int off = 32; off >= 1; off >>= 1) {
        s  += __shfl_down(s,  off, 64);
        ss += __shfl_down(ss, off, 64);
    }
    __shared__ float ls[4], lss[4];
    const int wid = i >> 6;
    if ((i & 63) == 0) { ls[wid] = s; lss[wid] = ss; }
    __syncthreads();

    const float tot   = ls[0]  + ls[1]  + ls[2]  + ls[3];
    const float totss = lss[0] + lss[1] + lss[2] + lss[3];

    const float mu  = tot * (1.0f / D_DIM);
    const float var = totss * (1.0f / D_DIM) - mu * mu;
    const float inv = 1.0f / sqrtf(var + 1e-5f);

    out[b * D_DIM + i] = (y - mu) * inv * gamma[i] + beta[i];
}

extern "C" void kernel_launch(void* const* d_in, const int* in_sizes, int n_in,
                              void* d_out, int out_size, void* d_ws, size_t ws_size,
                              hipStream_t stream) {
    // setup_inputs order: x, Wq, bq, Wk, bk, Wv, bv, gamma, beta
    const float* x     = (const float*)d_in[0];
    const float* Wv    = (const float*)d_in[5];
    const float* bv    = (const float*)d_in[6];
    const float* gamma = (const float*)d_in[7];
    const float* beta  = (const float*)d_in[8];
    float* out = (float*)d_out;

    ufl_collapsed_kernel<<<B_DIM, D_DIM, 0, stream>>>(x, Wv, bv, gamma, beta, out);
}